// Round 11
// baseline (126.954 us; speedup 1.0000x reference)
//
#include <hip/hip_runtime.h>

// RelativePositionalEncoding2D: out[b,i,j,e] = W[e, pos] + bias[e]
//   pos = clip(idxs[b,j] - idxs[b,i], -32, 32) + 32
// Shapes: B=1, S=1024, E=128, N=65. Output fp32 (1,S,S,E) = 512 MiB -> pure
// HBM-write-bound (floor ~80us at ~6.7 TB/s measured fill BW).
//
// R10 -> R11: GRID-STRIDE the output like the fill kernel. All prior probes
// kept 1024 resident blocks each owning a private far-apart stream (window =
// 1024 scattered pointers over 512 MiB). The fill kernel -- 84% of peak at
// 3.4 waves/CU -- grid-strides, so the whole grid writes ONE dense rolling
// window (near-sequential DRAM line addresses -> page hits). Here each wave
// writes 2 rows (1 KiB) per step and strides by the grid footprint (16384
// rows); i = r>>10, j = r&1023 are shift/mask; idxs staged once in LDS
// serves both i and j lookups. Table prologue, plain stores from R6.

#define MAXGAP 32
#define NIDX   65     // 2*MAXGAP+1
#define EDIM   128
#define E4     32     // EDIM/4 float4 per output row
#define PADE   132    // padded row stride in floats (528B, 16B-aligned)
#define WPB    4      // waves per 256-thread block

typedef float f32x4 __attribute__((ext_vector_type(4)));

__global__ __launch_bounds__(256) void relpos2d_kernel(
    const int* __restrict__ idxs,
    const float* __restrict__ W,       // (E, N) row-major
    const float* __restrict__ bias,    // (E,)
    f32x4* __restrict__ out,           // (S*S, E4)
    int S, int logS, int totalRows)
{
    __shared__ float table[NIDX * PADE];  // 34,320 B
    __shared__ int   sidx[1024];          // full idxs vector (4 KiB)

    // table[p][e] = W[e*N + p] + bias[e]; read W coalesced, scatter to LDS.
    for (int t = threadIdx.x; t < NIDX * EDIM; t += 256) {
        float w = W[t];              // coalesced: t = e*NIDX + p
        int e = t / NIDX;            // magic-mul (constant divisor)
        int p = t - e * NIDX;
        table[p * PADE + e] = w + bias[e];
    }

    // stage the whole idxs vector (serves both i and j lookups)
    for (int t = threadIdx.x; t < S; t += 256)
        sidx[t] = idxs[t];

    __syncthreads();

    const int lane  = threadIdx.x & 63;
    const int lane4 = lane & 31;          // float4 slot within a 512B row
    const int half  = lane >> 5;          // 0/1: which of the wave's 2 rows
    const int wid   = blockIdx.x * WPB + (threadIdx.x >> 6);  // global wave
    const int rowsPerStep = gridDim.x * WPB * 2;              // 16384

    #pragma unroll 4
    for (int r0 = wid * 2; r0 < totalRows; r0 += rowsPerStep) {
        int r = r0 + half;                 // this half-wave's output row
        int i = r >> logS;
        int j = r & (S - 1);

        int d = sidx[j] - sidx[i];         // LDS (broadcast per half-wave)
        d = d < -MAXGAP ? -MAXGAP : (d > MAXGAP ? MAXGAP : d);
        int p = d + MAXGAP;

        f32x4 v = reinterpret_cast<const f32x4*>(&table[p * PADE])[lane4];
        out[(size_t)r * E4 + lane4] = v;   // wave: 64 consecutive f32x4 = 1 KiB
    }
}

extern "C" void kernel_launch(void* const* d_in, const int* in_sizes, int n_in,
                              void* d_out, int out_size, void* d_ws, size_t ws_size,
                              hipStream_t stream) {
    const int*   idxs = (const int*)  d_in[0];   // (B*S,) int32, B=1
    const float* W    = (const float*)d_in[1];   // (E, N) fp32
    const float* bias = (const float*)d_in[2];   // (E,)  fp32

    f32x4* out = (f32x4*)d_out;

    const int S         = in_sizes[0];   // B=1, power of two (1024)
    int logS = 0; while ((1 << logS) < S) ++logS;
    const int totalRows = S * S;
    const int grid      = 2048;          // 8192 waves; dense rolling window

    relpos2d_kernel<<<grid, 256, 0, stream>>>(
        idxs, W, bias, out, S, logS, totalRows);
}

// Round 12
// 95.882 us; speedup vs baseline: 1.3241x; 1.3241x over previous
//
#include <hip/hip_runtime.h>

// RelativePositionalEncoding2D: out[b,i,j,e] = W[e, pos] + bias[e]
//   pos = clip(idxs[b,j] - idxs[b,i], -32, 32) + 32
// Shapes: B=1, S=1024, E=128, N=65. Output fp32 (1,S,S,E) = 512 MiB -> pure
// HBM-write-bound (floor ~80us at ~6.7 TB/s measured fill BW).
//
// R11 -> R12: single variable on R6 (champion, 96.96us): block 256 -> 512
// threads. Same grid=2048, same 256KiB-per-block stream geometry (the best
// found: R9 sparser=105, R10 finer=99.5, R11 interleaved=127), but 4
// blocks/CU x 512 thr = 32 waves/CU (was 16) -> double the CU-level pool of
// outstanding dependent stores. Theory: fill kernel's 84% comes from deep
// store pipelining; ours is capped at ~unroll x waves; doubling waves is the
// remaining TLP lever (R8 tested blocks/CU but conflated with L1 table).

#define MAXGAP 32
#define NIDX   65     // 2*MAXGAP+1
#define EDIM   128
#define E4     32     // EDIM/4 float4 per output row
#define PADE   132    // padded row stride in floats (528B, 16B-aligned)
#define CHUNKS 2      // half-rows per i
#define BLK    512    // threads per block (16 rows in flight per iteration)

typedef float f32x4 __attribute__((ext_vector_type(4)));

__global__ __launch_bounds__(BLK) void relpos2d_kernel(
    const int* __restrict__ idxs,
    const float* __restrict__ W,       // (E, N) row-major
    const float* __restrict__ bias,    // (E,)
    f32x4* __restrict__ out,           // (S*S, E4)
    int S, int halfS)
{
    __shared__ float table[NIDX * PADE];  // 65*132*4 = 34,320 B
    __shared__ int   jidx[512];           // halfS entries

    // table[p][e] = W[e*N + p] + bias[e]; read W coalesced, scatter to LDS.
    for (int t = threadIdx.x; t < NIDX * EDIM; t += BLK) {
        float w = W[t];              // coalesced: t = e*NIDX + p
        int e = t / NIDX;            // magic-mul (constant divisor)
        int p = t - e * NIDX;
        table[p * PADE + e] = w + bias[e];
    }

    const int i     = blockIdx.x >> 1;       // CHUNKS == 2
    const int chunk = blockIdx.x & (CHUNKS - 1);
    const int jbase = chunk * halfS;

    // stage this block's idxs[j] slice
    for (int t = threadIdx.x; t < halfS; t += BLK)
        jidx[t] = idxs[jbase + t];

    __syncthreads();

    const int lane4 = threadIdx.x & 31;   // float4 slot within the 512B row
    const int jsub  = threadIdx.x >> 5;   // 0..15: j within this step
    const int idx_i = idxs[i];

    f32x4* __restrict__ orow = out + (size_t)i * S * E4 + (size_t)jbase * E4;

    #pragma unroll 4
    for (int jj = 0; jj < halfS; jj += BLK / 32) {
        int j = jj + jsub;
        int d = jidx[j] - idx_i;                       // LDS broadcast read
        d = d < -MAXGAP ? -MAXGAP : (d > MAXGAP ? MAXGAP : d);
        int p = d + MAXGAP;

        f32x4 v = reinterpret_cast<const f32x4*>(&table[p * PADE])[lane4];
        orow[(size_t)j * E4 + lane4] = v;              // plain store
    }
}

extern "C" void kernel_launch(void* const* d_in, const int* in_sizes, int n_in,
                              void* d_out, int out_size, void* d_ws, size_t ws_size,
                              hipStream_t stream) {
    const int*   idxs = (const int*)  d_in[0];   // (B*S,) int32, B=1
    const float* W    = (const float*)d_in[1];   // (E, N) fp32
    const float* bias = (const float*)d_in[2];   // (E,)  fp32

    f32x4* out = (f32x4*)d_out;

    const int S     = in_sizes[0];   // B=1
    const int halfS = S / 2;
    const int grid  = S * CHUNKS;    // 2048 blocks: one (i, half-row) tile each

    relpos2d_kernel<<<grid, BLK, 0, stream>>>(idxs, W, bias, out, S, halfS);
}

// Round 13
// 95.509 us; speedup vs baseline: 1.3292x; 1.0039x over previous
//
#include <hip/hip_runtime.h>

// RelativePositionalEncoding2D: out[b,i,j,e] = W[e, pos] + bias[e]
//   pos = clip(idxs[b,j] - idxs[b,i], -32, 32) + 32
// Shapes: B=1, S=1024, E=128, N=65. Output fp32 (1,S,S,E) = 512 MiB -> pure
// HBM-write-bound (floor ~80us at ~6.7 TB/s measured fill BW).
//
// R12 -> R13: single variable on R12 (champion, 95.88us): unroll 4 -> 8.
// Per-wave outstanding dependent ds_read->store pairs double (CU pool:
// 32 waves x 8 = 256). VGPR +16 stays under the 64-VGPR/8-waves-per-SIMD
// budget. Everything else byte-identical to R12 (512-thread blocks, 32
// waves/CU, 2048 blocks, 256KiB contiguous per block, plain stores).

#define MAXGAP 32
#define NIDX   65     // 2*MAXGAP+1
#define EDIM   128
#define E4     32     // EDIM/4 float4 per output row
#define PADE   132    // padded row stride in floats (528B, 16B-aligned)
#define CHUNKS 2      // half-rows per i
#define BLK    512    // threads per block (16 rows in flight per iteration)

typedef float f32x4 __attribute__((ext_vector_type(4)));

__global__ __launch_bounds__(BLK) void relpos2d_kernel(
    const int* __restrict__ idxs,
    const float* __restrict__ W,       // (E, N) row-major
    const float* __restrict__ bias,    // (E,)
    f32x4* __restrict__ out,           // (S*S, E4)
    int S, int halfS)
{
    __shared__ float table[NIDX * PADE];  // 65*132*4 = 34,320 B
    __shared__ int   jidx[512];           // halfS entries

    // table[p][e] = W[e*N + p] + bias[e]; read W coalesced, scatter to LDS.
    for (int t = threadIdx.x; t < NIDX * EDIM; t += BLK) {
        float w = W[t];              // coalesced: t = e*NIDX + p
        int e = t / NIDX;            // magic-mul (constant divisor)
        int p = t - e * NIDX;
        table[p * PADE + e] = w + bias[e];
    }

    const int i     = blockIdx.x >> 1;       // CHUNKS == 2
    const int chunk = blockIdx.x & (CHUNKS - 1);
    const int jbase = chunk * halfS;

    // stage this block's idxs[j] slice
    for (int t = threadIdx.x; t < halfS; t += BLK)
        jidx[t] = idxs[jbase + t];

    __syncthreads();

    const int lane4 = threadIdx.x & 31;   // float4 slot within the 512B row
    const int jsub  = threadIdx.x >> 5;   // 0..15: j within this step
    const int idx_i = idxs[i];

    f32x4* __restrict__ orow = out + (size_t)i * S * E4 + (size_t)jbase * E4;

    #pragma unroll 8
    for (int jj = 0; jj < halfS; jj += BLK / 32) {
        int j = jj + jsub;
        int d = jidx[j] - idx_i;                       // LDS broadcast read
        d = d < -MAXGAP ? -MAXGAP : (d > MAXGAP ? MAXGAP : d);
        int p = d + MAXGAP;

        f32x4 v = reinterpret_cast<const f32x4*>(&table[p * PADE])[lane4];
        orow[(size_t)j * E4 + lane4] = v;              // plain store
    }
}

extern "C" void kernel_launch(void* const* d_in, const int* in_sizes, int n_in,
                              void* d_out, int out_size, void* d_ws, size_t ws_size,
                              hipStream_t stream) {
    const int*   idxs = (const int*)  d_in[0];   // (B*S,) int32, B=1
    const float* W    = (const float*)d_in[1];   // (E, N) fp32
    const float* bias = (const float*)d_in[2];   // (E,)  fp32

    f32x4* out = (f32x4*)d_out;

    const int S     = in_sizes[0];   // B=1
    const int halfS = S / 2;
    const int grid  = S * CHUNKS;    // 2048 blocks: one (i, half-row) tile each

    relpos2d_kernel<<<grid, BLK, 0, stream>>>(idxs, W, bias, out, S, halfS);
}